// Round 5
// baseline (42.981 us; speedup 1.0000x reference)
//
#include <hip/hip_runtime.h>

#define NGRAM 4
#define KDIM 121
#define GDIM 5
#define FEPS 1e-9f
#define NKDIM (NGRAM * KDIM)      // 484 floats per [4,121] block
#define GNKDIM (GDIM * NKDIM)     // 2420
#define NCOMBO 81                 // 3^4
#define NV4 121                   // float4s per 484-float block
#define ITERS 4                   // elements per 128-thread group
#define CHUNK (2 * ITERS)         // elements per 256-thread block

__device__ __forceinline__ float pick3(int s, float x0, float x1, float x2) {
    return (s == 0) ? x0 : ((s == 1) ? x1 : x2);
}

__global__ __launch_bounds__(256, 4) void bleu_kernel(
    const float* __restrict__ tc_res,   // [B,1,4,121]
    const float* __restrict__ tc_gts,   // [B,5,4,121]
    const float* __restrict__ l_res,    // [B,1]
    const float* __restrict__ l_gts,    // [B,5]
    float* __restrict__ o_score,        // [B]
    float* __restrict__ o_slist,        // [B,81]
    float* __restrict__ o_judge,        // [B,4,121]
    float* __restrict__ o_sdl,          // [B]
    int B)
{
    const int tid  = threadIdx.x;
    const int half = tid >> 7;          // which group within the block
    const int t2   = tid & 127;         // index within the 128-thread group
    const int lane = tid & 63;
    const int wv   = (tid >> 6) & 1;    // which wave within the group

    // each group owns ITERS consecutive elements -> contiguous ~46 KB stream
    const int gbase = blockIdx.x * CHUNK + half * ITERS;

    __shared__ float4 red[2][2][2];     // [parity][half][wv]

    float4 cg, c0, c1, c2, c3, c4;
    float cl_i = 1.0f, clg0 = 0.f, clg1 = 0.f, clg2 = 0.f, clg3 = 0.f, clg4 = 0.f;

    // ---- prime the pipeline: element gbase ----
    {
        const int b = gbase;
        if (b < B) {
            if (t2 < NV4) {
                const float4* res4 = (const float4*)(tc_res + (size_t)b * NKDIM);
                const float4* gts4 = (const float4*)(tc_gts + (size_t)b * GNKDIM);
                cg = res4[t2];
                c0 = gts4[0 * NV4 + t2];
                c1 = gts4[1 * NV4 + t2];
                c2 = gts4[2 * NV4 + t2];
                c3 = gts4[3 * NV4 + t2];
                c4 = gts4[4 * NV4 + t2];
            }
            cl_i = l_res[b];
            clg0 = l_gts[(size_t)b * GDIM + 0];
            clg1 = l_gts[(size_t)b * GDIM + 1];
            clg2 = l_gts[(size_t)b * GDIM + 2];
            clg3 = l_gts[(size_t)b * GDIM + 3];
            clg4 = l_gts[(size_t)b * GDIM + 4];
        }
    }

    #pragma unroll
    for (int it = 0; it < ITERS; ++it) {
        const int b  = gbase + it;
        const int bn = gbase + it + 1;

        // ---- issue next element's loads EARLY (stay in flight across barrier) ----
        float4 ng, n0, n1, n2, n3, n4;
        float nl_i = 1.0f, nlg0 = 0.f, nlg1 = 0.f, nlg2 = 0.f, nlg3 = 0.f, nlg4 = 0.f;
        if (it + 1 < ITERS && bn < B) {
            if (t2 < NV4) {
                const float4* res4 = (const float4*)(tc_res + (size_t)bn * NKDIM);
                const float4* gts4 = (const float4*)(tc_gts + (size_t)bn * GNKDIM);
                ng = res4[t2];
                n0 = gts4[0 * NV4 + t2];
                n1 = gts4[1 * NV4 + t2];
                n2 = gts4[2 * NV4 + t2];
                n3 = gts4[3 * NV4 + t2];
                n4 = gts4[4 * NV4 + t2];
            }
            nl_i = l_res[bn];
            nlg0 = l_gts[(size_t)bn * GDIM + 0];
            nlg1 = l_gts[(size_t)bn * GDIM + 1];
            nlg2 = l_gts[(size_t)bn * GDIM + 2];
            nlg3 = l_gts[(size_t)bn * GDIM + 3];
            nlg4 = l_gts[(size_t)bn * GDIM + 4];
        }

        // ---- compute current element ----
        float a0 = 0.0f, a1 = 0.0f, a2 = 0.0f, a3 = 0.0f;
        if (b < B && t2 < NV4) {
            const float mx = fmaxf(fmaxf(fmaxf(c0.x, c1.x), fmaxf(c2.x, c3.x)), c4.x) + FEPS;
            const float my = fmaxf(fmaxf(fmaxf(c0.y, c1.y), fmaxf(c2.y, c3.y)), c4.y) + FEPS;
            const float mz = fmaxf(fmaxf(fmaxf(c0.z, c1.z), fmaxf(c2.z, c3.z)), c4.z) + FEPS;
            const float mw = fmaxf(fmaxf(fmaxf(c0.w, c1.w), fmaxf(c2.w, c3.w)), c4.w) + FEPS;

            float4 j;
            j.x = (cg.x <= mx) ? 1.0f : 0.0f;
            j.y = (cg.y <= my) ? 1.0f : 0.0f;
            j.z = (cg.z <= mz) ? 1.0f : 0.0f;
            j.w = (cg.w <= mw) ? 1.0f : 0.0f;
            ((float4*)(o_judge + (size_t)b * NKDIM))[t2] = j;

            const float cx = fminf(cg.x, mx);
            const float cy = fminf(cg.y, my);
            const float cz = fminf(cg.z, mz);
            const float cw = fminf(cg.w, mw);

            const int idx = t2 * 4;
            const int n0i = (idx >= KDIM) + (idx >= 2 * KDIM) + (idx >= 3 * KDIM);
            const int n3i = (idx + 3 >= KDIM) + (idx + 3 >= 2 * KDIM) + (idx + 3 >= 3 * KDIM);
            if (n0i == n3i) {
                const float s = (cx + cy) + (cz + cw);
                a0 += (n0i == 0) ? s : 0.0f;
                a1 += (n0i == 1) ? s : 0.0f;
                a2 += (n0i == 2) ? s : 0.0f;
                a3 += (n0i == 3) ? s : 0.0f;
            } else {
                const float ce[4] = { cx, cy, cz, cw };
                #pragma unroll
                for (int e = 0; e < 4; ++e) {
                    const int ie = idx + e;
                    const int ne = (ie >= KDIM) + (ie >= 2 * KDIM) + (ie >= 3 * KDIM);
                    const float v = ce[e];
                    a0 += (ne == 0) ? v : 0.0f;
                    a1 += (ne == 1) ? v : 0.0f;
                    a2 += (ne == 2) ? v : 0.0f;
                    a3 += (ne == 3) ? v : 0.0f;
                }
            }
        }

        // intra-wave reduction
        #pragma unroll
        for (int s = 1; s < 64; s <<= 1) {
            a0 += __shfl_xor(a0, s, 64);
            a1 += __shfl_xor(a1, s, 64);
            a2 += __shfl_xor(a2, s, 64);
            a3 += __shfl_xor(a3, s, 64);
        }

        // cross-wave combine (double-buffered by parity; one barrier per iter)
        const int p = it & 1;
        if (lane == 0) red[p][half][wv] = make_float4(a0, a1, a2, a3);
        __syncthreads();
        const float4 r0 = red[p][half][0];
        const float4 r1 = red[p][half][1];
        const float s0 = r0.x + r1.x;
        const float s1 = r0.y + r1.y;
        const float s2 = r0.z + r1.z;
        const float s3 = r0.w + r1.w;

        if (b < B) {
            // ---- scalar epilogue (redundant across the 128-thread group) ----
            float best_d = 1e30f;
            float l_r = 0.0f;
            const float lgs[GDIM] = { clg0, clg1, clg2, clg3, clg4 };
            #pragma unroll
            for (int g = 0; g < GDIM; ++g) {
                float lg = lgs[g];
                lg = (lg == 0.0f) ? 200.0f : lg;      // LEN_MAX*10
                const float d = fabsf(cl_i - lg);
                if (d < best_d) { best_d = d; l_r = lg; }   // strict < -> first argmin
            }

            const float li_e = cl_i + FEPS;
            const float und = 1.0f / li_e;
            const float r = (l_r + FEPS) / li_e;
            // In f32, 1.0+1e-9 == 1.0f (matches JAX f32 arithmetic)
            const float lf = expf(1.0f - fmaxf(1.0f, r));

            const float gf0 = s0 * und;
            const float gf1 = s1 * und;
            const float gf2 = s2 * und;
            const float gf3 = s3 * und;

            const float c00 = gf0, c01 = gf1, c02 = gf2, c03 = gf3;
            const float c10 = gf0 + und, c11 = gf1 + und, c12 = gf2 + und, c13 = gf3 + und;
            const float c20 = fmaxf(gf0 - und, 0.0f);
            const float c21 = fmaxf(gf1 - und, 0.0f);
            const float c22 = fmaxf(gf2 - und, 0.0f);
            const float c23 = fmaxf(gf3 - und, 0.0f);

            const float p_last = c20 * c21 * c22 * c23;
            const float cf_last = lf * sqrtf(sqrtf(p_last));

            if (t2 < NCOMBO) {
                const int c = t2;
                const int i = c / 27;
                const int j = (c / 9) % 3;
                const int kk = (c / 3) % 3;
                const int l = c % 3;
                const float pr = pick3(i, c00, c10, c20) *
                                 pick3(j, c01, c11, c21) *
                                 pick3(kk, c02, c12, c22) *
                                 pick3(l, c03, c13, c23);
                const float cf = lf * sqrtf(sqrtf(pr));
                o_slist[(size_t)b * NCOMBO + c] = cf - cf_last;
                if (c == 0) {
                    o_score[b] = cf;   // combo 0 is all-channel-0 = the score
                    const float base = gf0 * gf1 * gf2 * gf3;
                    // JAX max-tie gradient: w = 1 if r>1, 0.5 if r==1, 0 if r<1
                    const float w = (r > 1.0f) ? 1.0f : ((r == 1.0f) ? 0.5f : 0.0f);
                    o_sdl[b] = sqrtf(sqrtf(base)) * lf * w * (l_r + FEPS) / (li_e * li_e);
                }
            }
        }

        // rotate pipeline registers
        cg = ng; c0 = n0; c1 = n1; c2 = n2; c3 = n3; c4 = n4;
        cl_i = nl_i; clg0 = nlg0; clg1 = nlg1; clg2 = nlg2; clg3 = nlg3; clg4 = nlg4;
    }
}

extern "C" void kernel_launch(void* const* d_in, const int* in_sizes, int n_in,
                              void* d_out, int out_size, void* d_ws, size_t ws_size,
                              hipStream_t stream) {
    const float* tc_res = (const float*)d_in[0];
    const float* tc_gts = (const float*)d_in[1];
    const float* l_res  = (const float*)d_in[2];
    const float* l_gts  = (const float*)d_in[3];
    const int B = in_sizes[2];   // l_res has B elements

    float* out = (float*)d_out;
    float* o_score = out;
    float* o_slist = o_score + B;
    float* o_judge = o_slist + (size_t)B * NCOMBO;
    float* o_sdl   = o_judge + (size_t)B * NKDIM;

    const int blocks = (B + CHUNK - 1) / CHUNK;   // 8 elements per 256-thread block
    bleu_kernel<<<blocks, 256, 0, stream>>>(tc_res, tc_gts, l_res, l_gts,
                                            o_score, o_slist, o_judge, o_sdl, B);
}